// Round 7
// baseline (139.939 us; speedup 1.0000x reference)
//
#include <hip/hip_runtime.h>
#include <hip/hip_bf16.h>
#include <math.h>

// FeedForwardQuantum — Round 13: fused v3 = round-6 fused + T14 split of the
// h-production chain. Round 6 showed the fused kernel 2.5x above its pipe
// floor; the new serial chain per chunk was WLOAD->MFMA->pack->ds_write->
// barrier. Now: HCALC (mfma+pack, chunk i+2, into regs) is separated from
// HWRITE (ds_write of chunk i+1 packed LAST iteration) -> the MFMA/VALU
// latency hides under a full iteration. w1t prefetch depth 2 (wfE/wfO).
// Z/zf, B-staging, COMPUTE core, swizzle, epilogue: verbatim round-6
// (harness-verified, absmax 0.00390625). Same barrier structure.

typedef __attribute__((ext_vector_type(8))) short short8;
typedef __attribute__((ext_vector_type(8))) unsigned short ushort8;
typedef __attribute__((ext_vector_type(4))) float fx4;

constexpr int EDIM = 512;
constexpr int FDIM = 2048;
constexpr int NQ   = 10;
constexpr int BK   = 64;
constexpr int BM   = 128;
constexpr int BN   = 128;

__device__ __forceinline__ ushort f2bf(float f) {   // f32 -> bf16 RNE
    union { float f; unsigned u; } v; v.f = f;
    unsigned u = v.u + 0x7FFFu + ((v.u >> 16) & 1u);
    return (ushort)(u >> 16);
}
__device__ __forceinline__ float bf2f(ushort u) {
    union { unsigned u; float f; } v; v.u = (unsigned)u << 16; return v.f;
}
__device__ __forceinline__ unsigned bits2(__hip_bfloat162 h) {
    union { __hip_bfloat162 h; unsigned u; } v; v.h = h; return v.u;
}
__device__ __forceinline__ void gload_lds16(const void* g, void* l) {
    __builtin_amdgcn_global_load_lds(
        (const __attribute__((address_space(1))) void*)g,
        (__attribute__((address_space(3))) void*)l, 16, 0, 0);
}

// ---- prep: w2 f32->bf16 + split-precision w1t build (verbatim round-6) ----
__global__ void prep(const float* __restrict__ w2, const float* __restrict__ w1,
                     const float* __restrict__ b1,
                     ushort* __restrict__ w2b, ushort* __restrict__ w1t) {
    int gid = blockIdx.x * blockDim.x + threadIdx.x;
    int np  = gridDim.x * blockDim.x;
    for (int i = gid; i < EDIM * FDIM / 4; i += np) {
        float4 v = ((const float4*)w2)[i];
        ushort4 o; o.x = f2bf(v.x); o.y = f2bf(v.y); o.z = f2bf(v.z); o.w = f2bf(v.w);
        ((ushort4*)w2b)[i] = o;
    }
    for (int f = gid; f < FDIM; f += np) {
        ushort zr[32];
        #pragma unroll
        for (int w = 0; w < NQ; ++w) {
            float v  = w1[f * NQ + w];
            ushort hb = f2bf(v);
            ushort lb = f2bf(v - bf2f(hb));
            zr[w] = hb; zr[10 + w] = hb; zr[20 + w] = lb;
        }
        float bv  = b1[f];
        ushort bh = f2bf(bv);
        zr[30] = bh; zr[31] = f2bf(bv - bf2f(bh));
        #pragma unroll
        for (int u = 0; u < 4; ++u)
            *(ushort8*)&w1t[f * 32 + u * 8] = *(ushort8*)&zr[u * 8];
    }
}

// ---- fused: out = relu(q@w1^T+b1) @ w2^T + b2 ----
__global__ __launch_bounds__(256, 2) void fused(
    const float* __restrict__ x, const float* __restrict__ rx,
    const ushort* __restrict__ w1t,   // [FDIM][32] bf16 split-precision
    const ushort* __restrict__ w2b,   // [EDIM][FDIM] bf16
    const float* __restrict__ b2,
    float* __restrict__ out)
{
    __shared__ __align__(16) ushort Zs[BM * 32];       // 8 KiB
    __shared__ __align__(16) ushort As[2][BM * BK];    // 32 KiB (h tiles)
    __shared__ __align__(16) ushort Bs[2][BN * BK];    // 32 KiB (w2 tiles)

    const int tid = threadIdx.x;
    const int m0  = blockIdx.x * BM;
    const int n0  = blockIdx.y * BN;

    // ---- q prologue (verbatim) -> split bf16 Z rows ----
    if (tid < BM) {
        const float* xr = x + (size_t)(m0 + tid) * EDIM;
        float4 xa = *(const float4*)xr;
        float4 xb = *(const float4*)(xr + 4);
        float2 xc = *(const float2*)(xr + 8);
        float xv[NQ] = {xa.x, xa.y, xa.z, xa.w, xb.x, xb.y, xb.z, xb.w, xc.x, xc.y};
        float c[NQ], q[NQ];
        #pragma unroll
        for (int w = 0; w < NQ; ++w) c[w] = cosf(xv[w] + rx[w]);
        float p0 = c[1];
        #pragma unroll
        for (int w = 2; w < NQ; ++w) p0 *= c[w];
        q[0] = p0;
        float p = c[0];
        #pragma unroll
        for (int w = 1; w < NQ; ++w) { p *= c[w]; q[w] = p; }
        ushort zr[32];
        #pragma unroll
        for (int w = 0; w < NQ; ++w) {
            ushort hb = f2bf(q[w]);
            ushort lb = f2bf(q[w] - bf2f(hb));
            zr[w] = hb; zr[10 + w] = lb; zr[20 + w] = hb;
        }
        zr[30] = 0x3F80u; zr[31] = 0x3F80u;   // 1.0, 1.0
        #pragma unroll
        for (int u = 0; u < 4; ++u)
            *(ushort8*)&Zs[tid * 32 + u * 8] = *(ushort8*)&zr[u * 8];
    }
    __syncthreads();

    const int wave = tid >> 6, lane = tid & 63;
    const int quad = lane >> 4, l16 = lane & 15;
    const int wm   = wave >> 1, wn = wave & 1;
    const int swz  = l16 & 7;

    // H-production roles (verbatim round-6)
    const int hm0 = (wave & 1) * 64;
    const int hf0 = (wave >> 1) * 32;
    short8 zf[4];
    #pragma unroll
    for (int mi = 0; mi < 4; ++mi)
        zf[mi] = *(const short8*)&Zs[(hm0 + mi * 16 + l16) * 32 + quad * 8];

    // B staging (verbatim round-0/6)
    const int srow0 = tid >> 3;
    const int sbs   = tid & 7;
    const ushort* gB[4];
    #pragma unroll
    for (int u = 0; u < 4; ++u) {
        int row = u * 32 + srow0;
        int bl  = sbs ^ (row & 7);
        gB[u] = w2b + (size_t)(n0 + row) * FDIM + bl * 8;
    }
    const int ldst = wave * 512;

    // fragment-read offsets (verbatim)
    int aro[4], bro[4];
    #pragma unroll
    for (int t = 0; t < 4; ++t) {
        aro[t] = (wm * 64 + t * 16 + l16) * BK;
        bro[t] = (wn * 64 + t * 16 + l16) * BK;
    }

    fx4 acc[4][4];
    #pragma unroll
    for (int a = 0; a < 4; ++a)
        #pragma unroll
        for (int b = 0; b < 4; ++b) acc[a][b] = fx4{0.f, 0.f, 0.f, 0.f};

    short8 wfE[2], wfO[2];
    uint2  pE[4][2], pO[4][2];

#define WLOAD(WF, CH) do { _Pragma("unroll") \
    for (int fi = 0; fi < 2; ++fi) \
        WF[fi] = *(const short8*)(w1t + ((CH) * 64 + hf0 + fi * 16 + l16) * 32 + quad * 8); \
} while (0)

#define STAGEB(BUF) do { _Pragma("unroll") \
    for (int u = 0; u < 4; ++u) { gload_lds16(gB[u], &Bs[BUF][u * 2048 + ldst]); gB[u] += BK; } \
} while (0)

// h mfma + relu + bf16 pack into registers P (NO LDS write)
#define HCALC(P, WF) do { _Pragma("unroll") \
    for (int mi = 0; mi < 4; ++mi) \
        _Pragma("unroll") \
        for (int fi = 0; fi < 2; ++fi) { \
            fx4 hv = __builtin_amdgcn_mfma_f32_16x16x32_bf16( \
                WF[fi], zf[mi], fx4{0.f, 0.f, 0.f, 0.f}, 0, 0, 0); \
            unsigned ua = bits2(__float22bfloat162_rn( \
                make_float2(fmaxf(hv[0], 0.f), fmaxf(hv[1], 0.f)))); \
            unsigned ub = bits2(__float22bfloat162_rn( \
                make_float2(fmaxf(hv[2], 0.f), fmaxf(hv[3], 0.f)))); \
            P[mi][fi] = make_uint2(ua, ub); \
        } \
} while (0)

// write previously packed h tile into As[BUF] (addresses verbatim round-6)
#define HWRITE(BUF, P) do { _Pragma("unroll") \
    for (int mi = 0; mi < 4; ++mi) { \
        const int hrow = hm0 + mi * 16 + l16; \
        ushort* arow = &As[BUF][hrow * BK]; \
        _Pragma("unroll") \
        for (int fi = 0; fi < 2; ++fi) { \
            const int blk = (hf0 >> 3) + fi * 2 + (quad >> 1); \
            *(uint2*)&arow[((blk ^ swz) << 3) + ((quad & 1) << 2)] = P[mi][fi]; \
        } \
    } \
} while (0)

#define COMPUTE(BUF) do { \
    short8 af[4][2], bf[4][2]; \
    _Pragma("unroll") \
    for (int t = 0; t < 4; ++t) \
        _Pragma("unroll") \
        for (int hf = 0; hf < 2; ++hf) { \
            const int blkb = (((hf * 4 + quad) ^ swz) << 3); \
            af[t][hf] = *(const short8*)&As[BUF][aro[t] + blkb]; \
            bf[t][hf] = *(const short8*)&Bs[BUF][bro[t] + blkb]; \
        } \
    _Pragma("unroll") \
    for (int hf = 0; hf < 2; ++hf) \
        _Pragma("unroll") \
        for (int mt = 0; mt < 4; ++mt) \
            _Pragma("unroll") \
            for (int nt = 0; nt < 4; ++nt) \
                acc[mt][nt] = __builtin_amdgcn_mfma_f32_16x16x32_bf16( \
                    af[mt][hf], bf[nt][hf], acc[mt][nt], 0, 0, 0); \
} while (0)

    // ---- prologue: As[0]=h(0); pO=pack(1); wfE=w(2); wfO=w(3); Bs[0]=B(0) ----
    WLOAD(wfE, 0); WLOAD(wfO, 1);
    STAGEB(0);
    HCALC(pE, wfE); HWRITE(0, pE);
    HCALC(pO, wfO);
    WLOAD(wfE, 2); WLOAD(wfO, 3);
    __syncthreads();

    // ---- pairs p=0..13: compute (2p,2p+1); write (2p+1,2p+2); calc (2p+2,2p+3) ----
    for (int p = 0; p < 14; ++p) {
        STAGEB(1); HWRITE(1, pO); HCALC(pE, wfE); WLOAD(wfE, 2 * p + 4);
        COMPUTE(0); __syncthreads();
        STAGEB(0); HWRITE(0, pE); HCALC(pO, wfO); WLOAD(wfO, 2 * p + 5);
        COMPUTE(1); __syncthreads();
    }
    // ---- pair 14: compute 28,29; write 29,30; calc 30,31 (no wloads) ----
    STAGEB(1); HWRITE(1, pO); HCALC(pE, wfE);
    COMPUTE(0); __syncthreads();
    STAGEB(0); HWRITE(0, pE); HCALC(pO, wfO);
    COMPUTE(1); __syncthreads();
    // ---- tail: stage 31, write 31, compute 30 then 31 ----
    STAGEB(1); HWRITE(1, pO);
    COMPUTE(0); __syncthreads();
    COMPUTE(1);

#undef COMPUTE
#undef HWRITE
#undef HCALC
#undef STAGEB
#undef WLOAD

    // ---- epilogue: + b2 (verbatim, harness-verified layout) ----
    float bb[4];
    #pragma unroll
    for (int nt = 0; nt < 4; ++nt) bb[nt] = b2[n0 + wn * 64 + nt * 16 + l16];
    #pragma unroll
    for (int mt = 0; mt < 4; ++mt) {
        const int mbase = m0 + wm * 64 + mt * 16 + quad * 4;
        #pragma unroll
        for (int nt = 0; nt < 4; ++nt) {
            const int n = n0 + wn * 64 + nt * 16 + l16;
            #pragma unroll
            for (int r = 0; r < 4; ++r)
                out[(size_t)(mbase + r) * EDIM + n] = acc[mt][nt][r] + bb[nt];
        }
    }
}

extern "C" void kernel_launch(void* const* d_in, const int* in_sizes, int n_in,
                              void* d_out, int out_size, void* d_ws, size_t ws_size,
                              hipStream_t stream) {
    const float* x  = (const float*)d_in[0];
    const float* rx = (const float*)d_in[1];
    const float* w1 = (const float*)d_in[2];
    const float* b1 = (const float*)d_in[3];
    const float* w2 = (const float*)d_in[4];
    const float* b2 = (const float*)d_in[5];
    float* out = (float*)d_out;

    const int M = in_sizes[0] / EDIM;   // 16384

    ushort* w2b = (ushort*)d_ws;                                    // 2 MiB
    ushort* w1t = (ushort*)((char*)d_ws + (size_t)EDIM * FDIM * 2); // 128 KiB
    (void)ws_size; (void)n_in; (void)out_size;

    hipLaunchKernelGGL(prep, dim3(256), dim3(256), 0, stream, w2, w1, b1, w2b, w1t);
    hipLaunchKernelGGL(fused, dim3(M / BM, EDIM / BN), dim3(256), 0, stream,
                       x, rx, w1t, w2b, b2, out);
}

// Round 8
// 132.774 us; speedup vs baseline: 1.0540x; 1.0540x over previous
//
#include <hip/hip_runtime.h>
#include <hip/hip_bf16.h>
#include <math.h>

// FeedForwardQuantum — Round 14: round-7 fused + (1) HCALC pack via HW
// v_cvt_pk_bf16_f32 (RNE, bit-identical; replaces ~190 VALU/thread/chunk of
// manual RNE bit-math with 16 instrs) + (2) setprio(1) around COMPUTE's MFMA
// cluster (T5). Theory: VALUBusy 36% (~850 cyc/chunk-unit) is dominated by
// __float22bfloat162_rn's manual lowering; removing it unblocks the VALU
// pipe that the h-chain added. All layout/barrier structure verbatim
// round-7 (harness-verified, absmax 0.00390625).

typedef __attribute__((ext_vector_type(8))) short short8;
typedef __attribute__((ext_vector_type(8))) unsigned short ushort8;
typedef __attribute__((ext_vector_type(4))) float fx4;

constexpr int EDIM = 512;
constexpr int FDIM = 2048;
constexpr int NQ   = 10;
constexpr int BK   = 64;
constexpr int BM   = 128;
constexpr int BN   = 128;

__device__ __forceinline__ ushort f2bf(float f) {   // f32 -> bf16 RNE
    union { float f; unsigned u; } v; v.f = f;
    unsigned u = v.u + 0x7FFFu + ((v.u >> 16) & 1u);
    return (ushort)(u >> 16);
}
__device__ __forceinline__ float bf2f(ushort u) {
    union { unsigned u; float f; } v; v.u = (unsigned)u << 16; return v.f;
}
__device__ __forceinline__ unsigned bits2(__hip_bfloat162 h) {
    union { __hip_bfloat162 h; unsigned u; } v; v.h = h; return v.u;
}
// HW packed f32x2 -> bf16x2, round-to-nearest-even (same as f2bf pair)
__device__ __forceinline__ unsigned cvtpk(float lo, float hi) {
    unsigned r;
    asm("v_cvt_pk_bf16_f32 %0, %1, %2" : "=v"(r) : "v"(lo), "v"(hi));
    return r;
}
__device__ __forceinline__ void gload_lds16(const void* g, void* l) {
    __builtin_amdgcn_global_load_lds(
        (const __attribute__((address_space(1))) void*)g,
        (__attribute__((address_space(3))) void*)l, 16, 0, 0);
}

// ---- prep: w2 f32->bf16 + split-precision w1t build (verbatim round-6) ----
__global__ void prep(const float* __restrict__ w2, const float* __restrict__ w1,
                     const float* __restrict__ b1,
                     ushort* __restrict__ w2b, ushort* __restrict__ w1t) {
    int gid = blockIdx.x * blockDim.x + threadIdx.x;
    int np  = gridDim.x * blockDim.x;
    for (int i = gid; i < EDIM * FDIM / 4; i += np) {
        float4 v = ((const float4*)w2)[i];
        ushort4 o; o.x = f2bf(v.x); o.y = f2bf(v.y); o.z = f2bf(v.z); o.w = f2bf(v.w);
        ((ushort4*)w2b)[i] = o;
    }
    for (int f = gid; f < FDIM; f += np) {
        ushort zr[32];
        #pragma unroll
        for (int w = 0; w < NQ; ++w) {
            float v  = w1[f * NQ + w];
            ushort hb = f2bf(v);
            ushort lb = f2bf(v - bf2f(hb));
            zr[w] = hb; zr[10 + w] = hb; zr[20 + w] = lb;
        }
        float bv  = b1[f];
        ushort bh = f2bf(bv);
        zr[30] = bh; zr[31] = f2bf(bv - bf2f(bh));
        #pragma unroll
        for (int u = 0; u < 4; ++u)
            *(ushort8*)&w1t[f * 32 + u * 8] = *(ushort8*)&zr[u * 8];
    }
}

// ---- fused: out = relu(q@w1^T+b1) @ w2^T + b2 ----
__global__ __launch_bounds__(256, 2) void fused(
    const float* __restrict__ x, const float* __restrict__ rx,
    const ushort* __restrict__ w1t,   // [FDIM][32] bf16 split-precision
    const ushort* __restrict__ w2b,   // [EDIM][FDIM] bf16
    const float* __restrict__ b2,
    float* __restrict__ out)
{
    __shared__ __align__(16) ushort Zs[BM * 32];       // 8 KiB
    __shared__ __align__(16) ushort As[2][BM * BK];    // 32 KiB (h tiles)
    __shared__ __align__(16) ushort Bs[2][BN * BK];    // 32 KiB (w2 tiles)

    const int tid = threadIdx.x;
    const int m0  = blockIdx.x * BM;
    const int n0  = blockIdx.y * BN;

    // ---- q prologue (verbatim) -> split bf16 Z rows ----
    if (tid < BM) {
        const float* xr = x + (size_t)(m0 + tid) * EDIM;
        float4 xa = *(const float4*)xr;
        float4 xb = *(const float4*)(xr + 4);
        float2 xc = *(const float2*)(xr + 8);
        float xv[NQ] = {xa.x, xa.y, xa.z, xa.w, xb.x, xb.y, xb.z, xb.w, xc.x, xc.y};
        float c[NQ], q[NQ];
        #pragma unroll
        for (int w = 0; w < NQ; ++w) c[w] = cosf(xv[w] + rx[w]);
        float p0 = c[1];
        #pragma unroll
        for (int w = 2; w < NQ; ++w) p0 *= c[w];
        q[0] = p0;
        float p = c[0];
        #pragma unroll
        for (int w = 1; w < NQ; ++w) { p *= c[w]; q[w] = p; }
        ushort zr[32];
        #pragma unroll
        for (int w = 0; w < NQ; ++w) {
            ushort hb = f2bf(q[w]);
            ushort lb = f2bf(q[w] - bf2f(hb));
            zr[w] = hb; zr[10 + w] = lb; zr[20 + w] = hb;
        }
        zr[30] = 0x3F80u; zr[31] = 0x3F80u;   // 1.0, 1.0
        #pragma unroll
        for (int u = 0; u < 4; ++u)
            *(ushort8*)&Zs[tid * 32 + u * 8] = *(ushort8*)&zr[u * 8];
    }
    __syncthreads();

    const int wave = tid >> 6, lane = tid & 63;
    const int quad = lane >> 4, l16 = lane & 15;
    const int wm   = wave >> 1, wn = wave & 1;
    const int swz  = l16 & 7;

    // H-production roles (verbatim round-6/7)
    const int hm0 = (wave & 1) * 64;
    const int hf0 = (wave >> 1) * 32;
    short8 zf[4];
    #pragma unroll
    for (int mi = 0; mi < 4; ++mi)
        zf[mi] = *(const short8*)&Zs[(hm0 + mi * 16 + l16) * 32 + quad * 8];

    // B staging (verbatim round-0/6/7)
    const int srow0 = tid >> 3;
    const int sbs   = tid & 7;
    const ushort* gB[4];
    #pragma unroll
    for (int u = 0; u < 4; ++u) {
        int row = u * 32 + srow0;
        int bl  = sbs ^ (row & 7);
        gB[u] = w2b + (size_t)(n0 + row) * FDIM + bl * 8;
    }
    const int ldst = wave * 512;

    // fragment-read offsets (verbatim)
    int aro[4], bro[4];
    #pragma unroll
    for (int t = 0; t < 4; ++t) {
        aro[t] = (wm * 64 + t * 16 + l16) * BK;
        bro[t] = (wn * 64 + t * 16 + l16) * BK;
    }

    fx4 acc[4][4];
    #pragma unroll
    for (int a = 0; a < 4; ++a)
        #pragma unroll
        for (int b = 0; b < 4; ++b) acc[a][b] = fx4{0.f, 0.f, 0.f, 0.f};

    const fx4 zacc = fx4{0.f, 0.f, 0.f, 0.f};   // hoisted zero C-operand

    short8 wfE[2], wfO[2];
    uint2  pE[4][2], pO[4][2];

#define WLOAD(WF, CH) do { _Pragma("unroll") \
    for (int fi = 0; fi < 2; ++fi) \
        WF[fi] = *(const short8*)(w1t + ((CH) * 64 + hf0 + fi * 16 + l16) * 32 + quad * 8); \
} while (0)

#define STAGEB(BUF) do { _Pragma("unroll") \
    for (int u = 0; u < 4; ++u) { gload_lds16(gB[u], &Bs[BUF][u * 2048 + ldst]); gB[u] += BK; } \
} while (0)

// h mfma + relu + HW cvt_pk bf16 pack into registers P (no LDS write)
#define HCALC(P, WF) do { _Pragma("unroll") \
    for (int mi = 0; mi < 4; ++mi) \
        _Pragma("unroll") \
        for (int fi = 0; fi < 2; ++fi) { \
            fx4 hv = __builtin_amdgcn_mfma_f32_16x16x32_bf16( \
                WF[fi], zf[mi], zacc, 0, 0, 0); \
            unsigned ua = cvtpk(fmaxf(hv[0], 0.f), fmaxf(hv[1], 0.f)); \
            unsigned ub = cvtpk(fmaxf(hv[2], 0.f), fmaxf(hv[3], 0.f)); \
            P[mi][fi] = make_uint2(ua, ub); \
        } \
} while (0)

// write previously packed h tile into As[BUF] (addresses verbatim round-6/7)
#define HWRITE(BUF, P) do { _Pragma("unroll") \
    for (int mi = 0; mi < 4; ++mi) { \
        const int hrow = hm0 + mi * 16 + l16; \
        ushort* arow = &As[BUF][hrow * BK]; \
        _Pragma("unroll") \
        for (int fi = 0; fi < 2; ++fi) { \
            const int blk = (hf0 >> 3) + fi * 2 + (quad >> 1); \
            *(uint2*)&arow[((blk ^ swz) << 3) + ((quad & 1) << 2)] = P[mi][fi]; \
        } \
    } \
} while (0)

#define COMPUTE(BUF) do { \
    short8 af[4][2], bf[4][2]; \
    _Pragma("unroll") \
    for (int t = 0; t < 4; ++t) \
        _Pragma("unroll") \
        for (int hf = 0; hf < 2; ++hf) { \
            const int blkb = (((hf * 4 + quad) ^ swz) << 3); \
            af[t][hf] = *(const short8*)&As[BUF][aro[t] + blkb]; \
            bf[t][hf] = *(const short8*)&Bs[BUF][bro[t] + blkb]; \
        } \
    __builtin_amdgcn_s_setprio(1); \
    _Pragma("unroll") \
    for (int hf = 0; hf < 2; ++hf) \
        _Pragma("unroll") \
        for (int mt = 0; mt < 4; ++mt) \
            _Pragma("unroll") \
            for (int nt = 0; nt < 4; ++nt) \
                acc[mt][nt] = __builtin_amdgcn_mfma_f32_16x16x32_bf16( \
                    af[mt][hf], bf[nt][hf], acc[mt][nt], 0, 0, 0); \
    __builtin_amdgcn_s_setprio(0); \
} while (0)

    // ---- prologue: As[0]=h(0); pO=pack(1); wfE=w(2); wfO=w(3); Bs[0]=B(0) ----
    WLOAD(wfE, 0); WLOAD(wfO, 1);
    STAGEB(0);
    HCALC(pE, wfE); HWRITE(0, pE);
    HCALC(pO, wfO);
    WLOAD(wfE, 2); WLOAD(wfO, 3);
    __syncthreads();

    // ---- pairs p=0..13: compute (2p,2p+1); write (2p+1,2p+2); calc (2p+2,2p+3) ----
    for (int p = 0; p < 14; ++p) {
        STAGEB(1); HWRITE(1, pO); HCALC(pE, wfE); WLOAD(wfE, 2 * p + 4);
        COMPUTE(0); __syncthreads();
        STAGEB(0); HWRITE(0, pE); HCALC(pO, wfO); WLOAD(wfO, 2 * p + 5);
        COMPUTE(1); __syncthreads();
    }
    // ---- pair 14: compute 28,29; write 29,30; calc 30,31 (no wloads) ----
    STAGEB(1); HWRITE(1, pO); HCALC(pE, wfE);
    COMPUTE(0); __syncthreads();
    STAGEB(0); HWRITE(0, pE); HCALC(pO, wfO);
    COMPUTE(1); __syncthreads();
    // ---- tail: stage 31, write 31, compute 30 then 31 ----
    STAGEB(1); HWRITE(1, pO);
    COMPUTE(0); __syncthreads();
    COMPUTE(1);

#undef COMPUTE
#undef HWRITE
#undef HCALC
#undef STAGEB
#undef WLOAD

    // ---- epilogue: + b2 (verbatim, harness-verified layout) ----
    float bb[4];
    #pragma unroll
    for (int nt = 0; nt < 4; ++nt) bb[nt] = b2[n0 + wn * 64 + nt * 16 + l16];
    #pragma unroll
    for (int mt = 0; mt < 4; ++mt) {
        const int mbase = m0 + wm * 64 + mt * 16 + quad * 4;
        #pragma unroll
        for (int nt = 0; nt < 4; ++nt) {
            const int n = n0 + wn * 64 + nt * 16 + l16;
            #pragma unroll
            for (int r = 0; r < 4; ++r)
                out[(size_t)(mbase + r) * EDIM + n] = acc[mt][nt][r] + bb[nt];
        }
    }
}

extern "C" void kernel_launch(void* const* d_in, const int* in_sizes, int n_in,
                              void* d_out, int out_size, void* d_ws, size_t ws_size,
                              hipStream_t stream) {
    const float* x  = (const float*)d_in[0];
    const float* rx = (const float*)d_in[1];
    const float* w1 = (const float*)d_in[2];
    const float* b1 = (const float*)d_in[3];
    const float* w2 = (const float*)d_in[4];
    const float* b2 = (const float*)d_in[5];
    float* out = (float*)d_out;

    const int M = in_sizes[0] / EDIM;   // 16384

    ushort* w2b = (ushort*)d_ws;                                    // 2 MiB
    ushort* w1t = (ushort*)((char*)d_ws + (size_t)EDIM * FDIM * 2); // 128 KiB
    (void)ws_size; (void)n_in; (void)out_size;

    hipLaunchKernelGGL(prep, dim3(256), dim3(256), 0, stream, w2, w1, b1, w2b, w1t);
    hipLaunchKernelGGL(fused, dim3(M / BM, EDIM / BN), dim3(256), 0, stream,
                       x, rx, w1t, w2b, b2, out);
}